// Round 2
// baseline (1706.126 us; speedup 1.0000x reference)
//
#include <hip/hip_runtime.h>
#include <math.h>

constexpr int N_VN   = 8000;
constexpr int N_CN   = 4000;
constexpr int DV     = 3;
constexpr int DC     = 6;
constexpr int EDGES  = N_VN * DV;   // 24000
constexpr int BATCH  = 1250;
constexpr int BP     = 1280;        // padded batch stride for ws arrays
constexpr int NUM_ITER = 5;
constexpr float LLR_MAX = 20.0f;
constexpr int NBLK_B = 5;           // ceil(1250/256)
constexpr int NPART  = NBLK_B * N_VN;  // vn_k blocks per iter = 40000

// log|tanh(mw/2)| with the reference's EPS=1e-12 floor, cancellation-free.
// Must be the SAME function in cn_k and vn_k so slog - lt cancels exactly.
__device__ __forceinline__ void edge_stats(float mv, float w, float& lt, int& neg) {
    float mw = fminf(fmaxf(mv * w, -LLR_MAX), LLR_MAX);
    neg = (mw < 0.0f) ? 1 : 0;
    float ex = __expf(-fabsf(mw));
    float u  = __fdividef(2.0f * ex, 1.0f + ex);      // 1 - |tanh(mw/2)|
    lt = (u < 1.0f) ? log1pf(-u) : -27.631021116f;    // log(1e-12) floor (mw==0)
}

// ---------------------------------------------------------------- graph build
__global__ __launch_bounds__(256) void build_graph_k(const int* __restrict__ cn_idx,
                                                     int* __restrict__ cnt,
                                                     int* __restrict__ cn_edges) {
    int e = blockIdx.x * 256 + threadIdx.x;
    if (e >= EDGES) return;
    int c = cn_idx[e];
    int slot = atomicAdd(&cnt[c], 1);   // order within CN irrelevant (sum commutes)
    cn_edges[c * DC + slot] = e;
}

// --------------------------------------------------- init: llr out + L = -llr^T
__global__ __launch_bounds__(256) void init_llr_k(const float* __restrict__ noise,
                                                  const int* __restrict__ ebno,
                                                  float* __restrict__ llr_out,
                                                  float* __restrict__ L) {
    __shared__ float tile[32][33];
    __shared__ float hs[2];
    int tx = threadIdx.x, ty = threadIdx.y;
    if (tx == 0 && ty == 0) {
        double sig2 = 2.0 * pow(10.0, (double)ebno[0] * 0.1);  // 4/no
        hs[0] = (float)(sig2 * 0.5);
        hs[1] = (float)sqrt(sig2);
    }
    __syncthreads();
    float h = hs[0], s = hs[1];
    int vbase = blockIdx.x * 32;
    int bbase = blockIdx.y * 32;
    #pragma unroll
    for (int j = 0; j < 4; ++j) {
        int v = vbase + tx;
        int b = bbase + ty + j * 8;
        if (b < BATCH) {
            float val = noise[b * N_VN + v];
            tile[ty + j * 8][tx] = val;               // tile[b_local][v_local]
            llr_out[b * N_VN + v] = -h + s * val;
        }
    }
    __syncthreads();
    #pragma unroll
    for (int j = 0; j < 4; ++j) {
        int b = bbase + tx;
        int v = vbase + ty + j * 8;
        if (b < BATCH) L[v * BP + b] = h - s * tile[tx][ty + j * 8];  // L = -llr^T
    }
}

// ------------------------------------------------------------------ CN update
template <bool FIRST>
__global__ __launch_bounds__(256) void cn_k(const float* __restrict__ msg_vn,
                                            const float* __restrict__ L,
                                            const float* __restrict__ weights,
                                            const int* __restrict__ cn_edges,
                                            float* __restrict__ slog,
                                            unsigned char* __restrict__ spar) {
    int b = blockIdx.x * 256 + threadIdx.x;
    int c = blockIdx.y;
    if (b >= BATCH) return;
    float sum_log = 0.0f;
    int negc = 0;
    #pragma unroll
    for (int j = 0; j < DC; ++j) {
        int e = cn_edges[c * DC + j];        // uniform per block -> scalar loads
        float w = weights[e];
        float mv = FIRST ? L[(e % N_VN) * BP + b] : msg_vn[e * BP + b];
        float lt; int neg;
        edge_stats(mv, w, lt, neg);
        sum_log += lt;
        negc += neg;
    }
    slog[c * BP + b] = sum_log;
    spar[c * BP + b] = (unsigned char)(negc & 1);
}

// ------------------------------------------------------------------ VN update
template <bool FIRST, bool LAST>
__global__ __launch_bounds__(256) void vn_k(float* __restrict__ msg_vn,
                                            const float* __restrict__ L,
                                            const float* __restrict__ weights,
                                            const int* __restrict__ cn_idx,
                                            const float* __restrict__ slog,
                                            const unsigned char* __restrict__ spar,
                                            float* __restrict__ xtot,
                                            float* __restrict__ loss_part) {
    int b = blockIdx.x * 256 + threadIdx.x;
    int v = blockIdx.y;
    float sp = 0.0f;
    if (b < BATCH) {
        float Lv = L[v * BP + b];
        float xt = Lv;
        float mc[DV];
        #pragma unroll
        for (int l = 0; l < DV; ++l) {
            int e = v + l * N_VN;            // vn_idx[e] == e % N_VN by construction
            int c = cn_idx[e];               // uniform per block -> scalar load
            float w = weights[e];
            float mv = FIRST ? Lv : msg_vn[e * BP + b];
            float lt; int neg;
            edge_stats(mv, w, lt, neg);
            float q = slog[c * BP + b] - lt;                 // sum over other edges (<= ~0)
            int par = ((int)spar[c * BP + b]) ^ neg;         // (sum_neg - neg) mod 2
            // 1 - mag without cancellation; clip prod at 1-1e-7 == floor omm at 1e-7
            float omm = fmaxf(-expm1f(q), 1e-7f);
            float msg = __logf(__fdividef(2.0f - omm, omm)); // 2*atanh(1-omm)
            if (par) msg = -msg;
            mc[l] = msg;
            xt += msg;
        }
        #pragma unroll
        for (int l = 0; l < DV; ++l)
            msg_vn[(v + l * N_VN) * BP + b] = xt - mc[l];
        if (LAST) xtot[v * 1250 + b] = xt;   // unpadded stride: fits exactly in c-region
        // softplus(-xt), numerically stable
        sp = fmaxf(-xt, 0.0f) + log1pf(__expf(-fabsf(xt)));
    }
    // block loss partial: wave shuffle + LDS, one private slot per block (no atomics)
    #pragma unroll
    for (int off = 32; off > 0; off >>= 1)
        sp += __shfl_down(sp, off, 64);
    __shared__ float red[4];
    int lane = threadIdx.x & 63;
    int wid  = threadIdx.x >> 6;
    if (lane == 0) red[wid] = sp;
    __syncthreads();
    if (threadIdx.x == 0)
        loss_part[blockIdx.y * gridDim.x + blockIdx.x] = red[0] + red[1] + red[2] + red[3];
}

// -------------------------------------------------- c_hat = -x_tot^T (tiled)
__global__ __launch_bounds__(256) void transpose_chat_k(const float* __restrict__ xtot,
                                                        float* __restrict__ chat) {
    __shared__ float tile[32][33];
    int bbase = blockIdx.x * 32;
    int vbase = blockIdx.y * 32;
    int tx = threadIdx.x, ty = threadIdx.y;
    #pragma unroll
    for (int j = 0; j < 4; ++j) {
        int v = vbase + ty + j * 8;
        int b = bbase + tx;
        if (b < BATCH) tile[ty + j * 8][tx] = xtot[v * 1250 + b];
    }
    __syncthreads();
    #pragma unroll
    for (int j = 0; j < 4; ++j) {
        int b = bbase + ty + j * 8;
        int v = vbase + tx;
        if (b < BATCH) chat[b * N_VN + v] = -tile[tx][ty + j * 8];
    }
}

__global__ __launch_bounds__(256) void finalize_loss_k(const float* __restrict__ lp,
                                                       float* __restrict__ out_loss) {
    double s = 0.0;
    for (int i = threadIdx.x; i < NUM_ITER * NPART; i += 256) s += (double)lp[i];
    #pragma unroll
    for (int off = 32; off > 0; off >>= 1)
        s += __shfl_down(s, off, 64);
    __shared__ double red[4];
    int lane = threadIdx.x & 63;
    int wid  = threadIdx.x >> 6;
    if (lane == 0) red[wid] = s;
    __syncthreads();
    if (threadIdx.x == 0)
        out_loss[0] = (float)((red[0] + red[1] + red[2] + red[3]) /
                              ((double)NUM_ITER * (double)BATCH * (double)N_VN));
}

// ---------------------------------------------------------------------- launch
extern "C" void kernel_launch(void* const* d_in, const int* in_sizes, int n_in,
                              void* d_out, int out_size, void* d_ws, size_t ws_size,
                              hipStream_t stream) {
    const float* noise   = (const float*)d_in[0];   // (1250, 8000)
    const float* weights = (const float*)d_in[1];   // (24000,)
    // d_in[2] = vn_idx (unused: vn_idx[e] == e % 8000 by construction)
    const int* cn_idx    = (const int*)d_in[3];     // (24000,)
    const int* ebno      = (const int*)d_in[4];     // scalar int

    float* out      = (float*)d_out;
    float* out_c    = out;                 // (1250,8000) zeros
    float* out_chat = out + 10000000;      // (1250,8000)
    float* out_llr  = out + 20000000;      // (1250,8000)
    float* out_loss = out + 30000000;      // scalar

    // workspace layout (~190.4 MB)
    char* ws = (char*)d_ws;
    float*         msg_vn    = (float*)(ws);                      // 24000*1280*4 = 122,880,000
    float*         L         = (float*)(ws + 122880000);          //  8000*1280*4 =  40,960,000
    float*         slog      = (float*)(ws + 163840000);          //  4000*1280*4 =  20,480,000
    unsigned char* spar      = (unsigned char*)(ws + 184320000);  //  4000*1280   =   5,120,000
    int*           cn_edges  = (int*)(ws + 189440000);            //  4000*6*4    =      96,000
    int*           cn_cnt    = (int*)(ws + 189536000);            //  4000*4      =      16,000
    float*         loss_part = (float*)(ws + 189552000);          //  5*40000*4   =     800,000
    float*         xtot      = out_c;  // stride 1250: exactly 10M floats, no overlap w/ chat

    hipMemsetAsync(cn_cnt, 0, N_CN * sizeof(int), stream);

    build_graph_k<<<dim3((EDGES + 255) / 256), dim3(256), 0, stream>>>(cn_idx, cn_cnt, cn_edges);
    init_llr_k<<<dim3(N_VN / 32, (BATCH + 31) / 32), dim3(32, 8), 0, stream>>>(noise, ebno, out_llr, L);

    dim3 gc(NBLK_B, N_CN), gv(NBLK_B, N_VN), blk(256);
    for (int it = 0; it < NUM_ITER; ++it) {
        bool first = (it == 0), last = (it == NUM_ITER - 1);
        float* lp = loss_part + it * NPART;   // write-only private slots: no memset needed
        if (first) cn_k<true ><<<gc, blk, 0, stream>>>(msg_vn, L, weights, cn_edges, slog, spar);
        else       cn_k<false><<<gc, blk, 0, stream>>>(msg_vn, L, weights, cn_edges, slog, spar);
        if (first)      vn_k<true , false><<<gv, blk, 0, stream>>>(msg_vn, L, weights, cn_idx, slog, spar, xtot, lp);
        else if (last)  vn_k<false, true ><<<gv, blk, 0, stream>>>(msg_vn, L, weights, cn_idx, slog, spar, xtot, lp);
        else            vn_k<false, false><<<gv, blk, 0, stream>>>(msg_vn, L, weights, cn_idx, slog, spar, xtot, lp);
    }

    transpose_chat_k<<<dim3((BATCH + 31) / 32, N_VN / 32), dim3(32, 8), 0, stream>>>(xtot, out_chat);
    hipMemsetAsync(out_c, 0, 10000000 * sizeof(float), stream);  // c = zeros (after xtot consumed)
    finalize_loss_k<<<1, 256, 0, stream>>>(loss_part, out_loss);
}

// Round 3
// 1186.107 us; speedup vs baseline: 1.4384x; 1.4384x over previous
//
#include <hip/hip_runtime.h>
#include <math.h>

constexpr int N_VN   = 8000;
constexpr int N_CN   = 4000;
constexpr int DV     = 3;
constexpr int DC     = 6;
constexpr int EDGES  = N_VN * DV;   // 24000
constexpr int BATCH  = 1250;
constexpr int BP     = 1280;        // padded batch stride (=320 float4)
constexpr int NUM_ITER = 5;
constexpr float LLR_MAX = 20.0f;
constexpr int TPB    = 320;         // 320 thr x 4 floats = 1280 = BP (5 waves)
constexpr int NPART  = NUM_ITER * N_VN;      // 40000 loss partials
constexpr float LOG_EPS = -27.631021116f;    // log(1e-12)

// Packed edge stat: s encodes lt = log(max(|tanh(mw/2)|,1e-12)) (always < 0)
// and neg = (mw < 0) in the sign bit:  s < 0 <=> neg;  lt = -|s|.
__device__ __forceinline__ float pack_stats(float mv, float w) {
    float mw = fminf(fmaxf(mv * w, -LLR_MAX), LLR_MAX);
    float ex = __expf(-fabsf(mw));
    float u  = __fdividef(2.0f * ex, 1.0f + ex);     // 1 - |tanh(mw/2)|
    float lt = fmaxf(log1pf(-u), LOG_EPS);           // u==1 -> -inf -> floor
    return (mw < 0.0f) ? lt : -lt;
}

// ---------------------------------------------------------------- graph build
__global__ __launch_bounds__(256) void build_graph_k(const int* __restrict__ cn_idx,
                                                     int* __restrict__ cnt,
                                                     int* __restrict__ cn_edges) {
    int e = blockIdx.x * 256 + threadIdx.x;
    if (e >= EDGES) return;
    int c = cn_idx[e];
    int slot = atomicAdd(&cnt[c], 1);   // order irrelevant (sum/parity commute)
    cn_edges[c * DC + slot] = e;
}

// --------------------------------------------------- init: llr out + L = -llr^T
__global__ __launch_bounds__(256) void init_llr_k(const float* __restrict__ noise,
                                                  const int* __restrict__ ebno,
                                                  float* __restrict__ llr_out,
                                                  float* __restrict__ L) {
    __shared__ float tile[32][33];
    __shared__ float hs[2];
    int tx = threadIdx.x, ty = threadIdx.y;
    if (tx == 0 && ty == 0) {
        double sig2 = 2.0 * pow(10.0, (double)ebno[0] * 0.1);  // 4/no
        hs[0] = (float)(sig2 * 0.5);
        hs[1] = (float)sqrt(sig2);
    }
    __syncthreads();
    float h = hs[0], s = hs[1];
    int vbase = blockIdx.x * 32;
    int bbase = blockIdx.y * 32;
    #pragma unroll
    for (int j = 0; j < 4; ++j) {
        int v = vbase + tx;
        int b = bbase + ty + j * 8;
        if (b < BATCH) {
            float val = noise[b * N_VN + v];
            tile[ty + j * 8][tx] = val;
            llr_out[b * N_VN + v] = -h + s * val;
        }
    }
    __syncthreads();
    #pragma unroll
    for (int j = 0; j < 4; ++j) {
        int b = bbase + tx;
        int v = vbase + ty + j * 8;
        if (b < BATCH) L[v * BP + b] = h - s * tile[tx][ty + j * 8];  // L=-llr^T
    }
}

// --------------------------------- iter 0 CN: stats from L, write ltn + slog
__global__ __launch_bounds__(TPB) void cn_first_k(const float* __restrict__ L,
                                                  const float* __restrict__ weights,
                                                  const int* __restrict__ cn_edges,
                                                  float* __restrict__ ltn,
                                                  float* __restrict__ slog) {
    int c = blockIdx.x;
    int b0 = threadIdx.x * 4;
    float sum[4] = {0.f, 0.f, 0.f, 0.f};
    int par[4] = {0, 0, 0, 0};
    #pragma unroll
    for (int j = 0; j < DC; ++j) {
        int e = cn_edges[c * DC + j];            // uniform -> scalar load
        int v = e; if (v >= 2 * N_VN) v -= 2 * N_VN; else if (v >= N_VN) v -= N_VN;
        float w = weights[e];
        float4 Lv = *(const float4*)(L + (size_t)v * BP + b0);
        float a[4] = {Lv.x, Lv.y, Lv.z, Lv.w};
        float o[4];
        #pragma unroll
        for (int k = 0; k < 4; ++k) {
            float s = pack_stats(a[k], w);
            o[k] = s;
            sum[k] -= fabsf(s);
            par[k] ^= (s < 0.0f) ? 1 : 0;
        }
        *(float4*)(ltn + (size_t)e * BP + b0) = make_float4(o[0], o[1], o[2], o[3]);
    }
    float o[4];
    #pragma unroll
    for (int k = 0; k < 4; ++k) o[k] = par[k] ? -sum[k] : sum[k];  // sign<->parity
    *(float4*)(slog + (size_t)c * BP + b0) = make_float4(o[0], o[1], o[2], o[3]);
}

// ------------------------------------------ CN: pure 6-term sum of packed stats
__global__ __launch_bounds__(TPB) void cn_k(const float* __restrict__ ltn,
                                            const int* __restrict__ cn_edges,
                                            float* __restrict__ slog) {
    int c = blockIdx.x;
    int b0 = threadIdx.x * 4;
    float sum[4] = {0.f, 0.f, 0.f, 0.f};
    int par[4] = {0, 0, 0, 0};
    #pragma unroll
    for (int j = 0; j < DC; ++j) {
        int e = cn_edges[c * DC + j];
        float4 s4 = *(const float4*)(ltn + (size_t)e * BP + b0);
        float a[4] = {s4.x, s4.y, s4.z, s4.w};
        #pragma unroll
        for (int k = 0; k < 4; ++k) {
            sum[k] -= fabsf(a[k]);
            par[k] ^= (a[k] < 0.0f) ? 1 : 0;
        }
    }
    float o[4];
    #pragma unroll
    for (int k = 0; k < 4; ++k) o[k] = par[k] ? -sum[k] : sum[k];
    *(float4*)(slog + (size_t)c * BP + b0) = make_float4(o[0], o[1], o[2], o[3]);
}

// ------------------------------------------------------------------ VN update
template <bool LAST>
__global__ __launch_bounds__(TPB) void vn_k(float* __restrict__ ltn,
                                            const float* __restrict__ L,
                                            const float* __restrict__ weights,
                                            const int* __restrict__ cn_idx,
                                            const float* __restrict__ slog,
                                            float* __restrict__ xtot,
                                            float* __restrict__ loss_part) {
    int v = blockIdx.x;
    int tid = threadIdx.x;
    int b0 = tid * 4;
    float4 Lv4 = *(const float4*)(L + (size_t)v * BP + b0);
    float xt[4] = {Lv4.x, Lv4.y, Lv4.z, Lv4.w};
    float mc[DV][4];
    #pragma unroll
    for (int l = 0; l < DV; ++l) {
        int e = v + l * N_VN;                // vn_idx[e] == e % N_VN
        int c = cn_idx[e];                   // uniform -> scalar load
        float4 s4 = *(const float4*)(ltn + (size_t)e * BP + b0);
        float4 S4 = *(const float4*)(slog + (size_t)c * BP + b0);
        float sa[4] = {s4.x, s4.y, s4.z, s4.w};
        float Sa[4] = {S4.x, S4.y, S4.z, S4.w};
        #pragma unroll
        for (int k = 0; k < 4; ++k) {
            float lt = -fabsf(sa[k]);
            int neg  = (sa[k] < 0.0f) ? 1 : 0;
            float q  = -fabsf(Sa[k]) - lt;                 // sum over other edges
            int par  = ((Sa[k] > 0.0f) ? 1 : 0) ^ neg;
            float omm = fmaxf(-expm1f(q), 1e-7f);          // 1-mag, clip at 1e-7
            float m = __logf(__fdividef(2.0f - omm, omm)); // 2*atanh(1-omm)
            m = par ? -m : m;
            mc[l][k] = m;
            xt[k] += m;
        }
    }
    if (!LAST) {
        // stats of next-iteration messages: msg_vn' = xt - mc
        #pragma unroll
        for (int l = 0; l < DV; ++l) {
            int e = v + l * N_VN;
            float w = weights[e];
            float o[4];
            #pragma unroll
            for (int k = 0; k < 4; ++k) o[k] = pack_stats(xt[k] - mc[l][k], w);
            *(float4*)(ltn + (size_t)e * BP + b0) = make_float4(o[0], o[1], o[2], o[3]);
        }
    } else {
        if (b0 + 3 < BATCH) {                // xtot stride 1250 (8B aligned only)
            *(float2*)(xtot + (size_t)v * BATCH + b0)     = make_float2(xt[0], xt[1]);
            *(float2*)(xtot + (size_t)v * BATCH + b0 + 2) = make_float2(xt[2], xt[3]);
        } else {
            #pragma unroll
            for (int k = 0; k < 4; ++k)
                if (b0 + k < BATCH) xtot[(size_t)v * BATCH + b0 + k] = xt[k];
        }
    }
    // loss partial (masked to valid batch), softplus(-xt) stable
    float sp = 0.0f;
    #pragma unroll
    for (int k = 0; k < 4; ++k)
        if (b0 + k < BATCH) {
            float x = xt[k];
            sp += fmaxf(-x, 0.0f) + log1pf(__expf(-fabsf(x)));
        }
    #pragma unroll
    for (int off = 32; off > 0; off >>= 1)
        sp += __shfl_down(sp, off, 64);
    __shared__ float red[5];
    int lane = tid & 63, wid = tid >> 6;
    if (lane == 0) red[wid] = sp;
    __syncthreads();
    if (tid == 0)
        loss_part[blockIdx.x] = red[0] + red[1] + red[2] + red[3] + red[4];
}

// -------------------------------------------------- c_hat = -x_tot^T (tiled)
__global__ __launch_bounds__(256) void transpose_chat_k(const float* __restrict__ xtot,
                                                        float* __restrict__ chat) {
    __shared__ float tile[32][33];
    int bbase = blockIdx.x * 32;
    int vbase = blockIdx.y * 32;
    int tx = threadIdx.x, ty = threadIdx.y;
    #pragma unroll
    for (int j = 0; j < 4; ++j) {
        int v = vbase + ty + j * 8;
        int b = bbase + tx;
        if (b < BATCH) tile[ty + j * 8][tx] = xtot[(size_t)v * BATCH + b];
    }
    __syncthreads();
    #pragma unroll
    for (int j = 0; j < 4; ++j) {
        int b = bbase + ty + j * 8;
        int v = vbase + tx;
        if (b < BATCH) chat[(size_t)b * N_VN + v] = -tile[tx][ty + j * 8];
    }
}

// ------------------------------------------------- loss: two-stage reduction
__global__ __launch_bounds__(256) void loss_stage1_k(const float* __restrict__ lp,
                                                     double* __restrict__ part) {
    double s = 0.0;
    for (int i = blockIdx.x * 256 + threadIdx.x; i < NPART; i += 64 * 256)
        s += (double)lp[i];
    #pragma unroll
    for (int off = 32; off > 0; off >>= 1)
        s += __shfl_down(s, off, 64);
    __shared__ double red[4];
    int lane = threadIdx.x & 63, wid = threadIdx.x >> 6;
    if (lane == 0) red[wid] = s;
    __syncthreads();
    if (threadIdx.x == 0) part[blockIdx.x] = red[0] + red[1] + red[2] + red[3];
}

__global__ __launch_bounds__(64) void loss_stage2_k(const double* __restrict__ part,
                                                    float* __restrict__ out_loss) {
    double s = part[threadIdx.x];
    #pragma unroll
    for (int off = 32; off > 0; off >>= 1)
        s += __shfl_down(s, off, 64);
    if (threadIdx.x == 0)
        out_loss[0] = (float)(s / ((double)NUM_ITER * (double)BATCH * (double)N_VN));
}

// ---------------------------------------------------------------------- launch
extern "C" void kernel_launch(void* const* d_in, const int* in_sizes, int n_in,
                              void* d_out, int out_size, void* d_ws, size_t ws_size,
                              hipStream_t stream) {
    const float* noise   = (const float*)d_in[0];   // (1250, 8000)
    const float* weights = (const float*)d_in[1];   // (24000,)
    // d_in[2] = vn_idx (unused: vn_idx[e] == e % 8000 by construction)
    const int* cn_idx    = (const int*)d_in[3];     // (24000,)
    const int* ebno      = (const int*)d_in[4];     // scalar int

    float* out      = (float*)d_out;
    float* out_c    = out;                 // (1250,8000) zeros
    float* out_chat = out + 10000000;      // (1250,8000)
    float* out_llr  = out + 20000000;      // (1250,8000)
    float* out_loss = out + 30000000;      // scalar

    // workspace layout (~184.6 MB)
    char* ws = (char*)d_ws;
    float*  ltn       = (float*)(ws);                    // 24000*1280*4 = 122,880,000
    float*  L         = (float*)(ws + 122880000);        //  8000*1280*4 =  40,960,000
    float*  slog      = (float*)(ws + 163840000);        //  4000*1280*4 =  20,480,000
    int*    cn_edges  = (int*)(ws + 184320000);          //  4000*6*4    =      96,000
    int*    cn_cnt    = (int*)(ws + 184416000);          //  4000*4      =      16,000
    float*  loss_part = (float*)(ws + 184432000);        //  5*8000*4    =     160,000
    double* loss_p2   = (double*)(ws + 184592000);       //  64*8        =         512
    float*  xtot      = out_c;  // stride 1250 = exactly 10M floats, no chat overlap

    hipMemsetAsync(cn_cnt, 0, N_CN * sizeof(int), stream);

    build_graph_k<<<dim3((EDGES + 255) / 256), dim3(256), 0, stream>>>(cn_idx, cn_cnt, cn_edges);
    init_llr_k<<<dim3(N_VN / 32, (BATCH + 31) / 32), dim3(32, 8), 0, stream>>>(noise, ebno, out_llr, L);

    for (int it = 0; it < NUM_ITER; ++it) {
        float* lp = loss_part + it * N_VN;   // write-only private slots
        if (it == 0)
            cn_first_k<<<dim3(N_CN), dim3(TPB), 0, stream>>>(L, weights, cn_edges, ltn, slog);
        else
            cn_k<<<dim3(N_CN), dim3(TPB), 0, stream>>>(ltn, cn_edges, slog);
        if (it == NUM_ITER - 1)
            vn_k<true ><<<dim3(N_VN), dim3(TPB), 0, stream>>>(ltn, L, weights, cn_idx, slog, xtot, lp);
        else
            vn_k<false><<<dim3(N_VN), dim3(TPB), 0, stream>>>(ltn, L, weights, cn_idx, slog, xtot, lp);
    }

    transpose_chat_k<<<dim3((BATCH + 31) / 32, N_VN / 32), dim3(32, 8), 0, stream>>>(xtot, out_chat);
    hipMemsetAsync(out_c, 0, 10000000 * sizeof(float), stream);  // c = zeros (after xtot read)
    loss_stage1_k<<<dim3(64), dim3(256), 0, stream>>>(loss_part, loss_p2);
    loss_stage2_k<<<dim3(1), dim3(64), 0, stream>>>(loss_p2, out_loss);
}

// Round 4
// 647.169 us; speedup vs baseline: 2.6363x; 1.8328x over previous
//
#include <hip/hip_runtime.h>
#include <math.h>

constexpr int N_VN   = 8000;
constexpr int N_CN   = 4000;
constexpr int DV     = 3;
constexpr int DC     = 6;
constexpr int EDGES  = N_VN * DV;   // 24000
constexpr int BATCH  = 1250;
constexpr int BP     = 1280;        // padded batch stride (=320 float4)
constexpr int NUM_ITER = 5;
constexpr float LLR_MAX = 20.0f;
constexpr int TPB    = 320;         // 320 thr x 4 floats = 1280 = BP (5 waves)
constexpr int NPART  = NUM_ITER * N_VN;      // 40000 loss partials
constexpr float LOG_EPS = -27.631021116f;    // log(1e-12)

// Packed edge stat: s encodes lt = log(max(|tanh(mw/2)|,1e-12)) and
// neg = (mw < 0) in the sign bit:  s < 0 <=> neg;  lt = -|s|.
// lt is clamped to <= -1e-9 so the sign bit is never ambiguous (and sums of
// lts stay strictly negative for cn_k's parity-in-sign-bit packing).
// All hw-trans: v_exp, v_rcp, v_log — conditioning matches the reference's
// own f32 tanh/log path (both round |t| to 1.0f for saturated messages).
__device__ __forceinline__ float pack_stats(float mv, float w) {
    float mw = fminf(fmaxf(mv * w, -LLR_MAX), LLR_MAX);
    float ex = __expf(-fabsf(mw));
    float t  = __fdividef(1.0f - ex, 1.0f + ex);     // |tanh(mw/2)|, 0 when mw==0
    float lt = fminf(fmaxf(__logf(t), LOG_EPS), -1e-9f);  // __logf(0)=-inf -> floor
    // sign bit <- (mw<0)
    unsigned sgn = __float_as_uint(mw) & 0x80000000u;
    return __uint_as_float((__float_as_uint(lt) ^ 0x80000000u) ^ sgn); // |lt| then flip if neg
}

// ---------------------------------------------------------------- graph build
__global__ __launch_bounds__(256) void build_graph_k(const int* __restrict__ cn_idx,
                                                     int* __restrict__ cnt,
                                                     int* __restrict__ cn_edges) {
    int e = blockIdx.x * 256 + threadIdx.x;
    if (e >= EDGES) return;
    int c = cn_idx[e];
    int slot = atomicAdd(&cnt[c], 1);   // order irrelevant (sum/parity commute)
    cn_edges[c * DC + slot] = e;
}

// --------------------------------------------------- init: llr out + L = -llr^T
__global__ __launch_bounds__(256) void init_llr_k(const float* __restrict__ noise,
                                                  const int* __restrict__ ebno,
                                                  float* __restrict__ llr_out,
                                                  float* __restrict__ L) {
    __shared__ float tile[32][33];
    __shared__ float hs[2];
    int tx = threadIdx.x, ty = threadIdx.y;
    if (tx == 0 && ty == 0) {
        double sig2 = 2.0 * pow(10.0, (double)ebno[0] * 0.1);  // 4/no
        hs[0] = (float)(sig2 * 0.5);
        hs[1] = (float)sqrt(sig2);
    }
    __syncthreads();
    float h = hs[0], s = hs[1];
    int vbase = blockIdx.x * 32;
    int bbase = blockIdx.y * 32;
    #pragma unroll
    for (int j = 0; j < 4; ++j) {
        int v = vbase + tx;
        int b = bbase + ty + j * 8;
        if (b < BATCH) {
            float val = noise[b * N_VN + v];
            tile[ty + j * 8][tx] = val;
            llr_out[b * N_VN + v] = -h + s * val;
        }
    }
    __syncthreads();
    #pragma unroll
    for (int j = 0; j < 4; ++j) {
        int b = bbase + tx;
        int v = vbase + ty + j * 8;
        if (b < BATCH) L[v * BP + b] = h - s * tile[tx][ty + j * 8];  // L=-llr^T
    }
}

// --------------------------------- iter 0 CN: stats from L, write ltn + slog
__global__ __launch_bounds__(TPB) void cn_first_k(const float* __restrict__ L,
                                                  const float* __restrict__ weights,
                                                  const int* __restrict__ cn_edges,
                                                  float* __restrict__ ltn,
                                                  float* __restrict__ slog) {
    int c = blockIdx.x;
    int b0 = threadIdx.x * 4;
    float sum[4] = {0.f, 0.f, 0.f, 0.f};
    unsigned px[4] = {0u, 0u, 0u, 0u};
    #pragma unroll
    for (int j = 0; j < DC; ++j) {
        int e = cn_edges[c * DC + j];            // uniform -> scalar load
        int v = e; if (v >= 2 * N_VN) v -= 2 * N_VN; else if (v >= N_VN) v -= N_VN;
        float w = weights[e];
        float4 Lv = *(const float4*)(L + (size_t)v * BP + b0);
        float a[4] = {Lv.x, Lv.y, Lv.z, Lv.w};
        float o[4];
        #pragma unroll
        for (int k = 0; k < 4; ++k) {
            float s = pack_stats(a[k], w);
            o[k] = s;
            sum[k] -= fabsf(s);
            px[k] ^= __float_as_uint(s);
        }
        *(float4*)(ltn + (size_t)e * BP + b0) = make_float4(o[0], o[1], o[2], o[3]);
    }
    float o[4];
    #pragma unroll
    for (int k = 0; k < 4; ++k)   // sum<0 strictly; flip sign bit if parity odd
        o[k] = __uint_as_float(__float_as_uint(sum[k]) ^ (px[k] & 0x80000000u));
    *(float4*)(slog + (size_t)c * BP + b0) = make_float4(o[0], o[1], o[2], o[3]);
}

// ------------------------------------------ CN: pure 6-term sum of packed stats
__global__ __launch_bounds__(TPB) void cn_k(const float* __restrict__ ltn,
                                            const int* __restrict__ cn_edges,
                                            float* __restrict__ slog) {
    int c = blockIdx.x;
    int b0 = threadIdx.x * 4;
    float sum[4] = {0.f, 0.f, 0.f, 0.f};
    unsigned px[4] = {0u, 0u, 0u, 0u};
    #pragma unroll
    for (int j = 0; j < DC; ++j) {
        int e = cn_edges[c * DC + j];
        float4 s4 = *(const float4*)(ltn + (size_t)e * BP + b0);
        float a[4] = {s4.x, s4.y, s4.z, s4.w};
        #pragma unroll
        for (int k = 0; k < 4; ++k) {
            sum[k] -= fabsf(a[k]);
            px[k] ^= __float_as_uint(a[k]);
        }
    }
    float o[4];
    #pragma unroll
    for (int k = 0; k < 4; ++k)
        o[k] = __uint_as_float(__float_as_uint(sum[k]) ^ (px[k] & 0x80000000u));
    *(float4*)(slog + (size_t)c * BP + b0) = make_float4(o[0], o[1], o[2], o[3]);
}

// ------------------------------------------------------------------ VN update
template <bool LAST>
__global__ __launch_bounds__(TPB) void vn_k(float* __restrict__ ltn,
                                            const float* __restrict__ L,
                                            const float* __restrict__ weights,
                                            const int* __restrict__ cn_idx,
                                            const float* __restrict__ slog,
                                            float* __restrict__ xtot,
                                            float* __restrict__ loss_part) {
    int v = blockIdx.x;
    int tid = threadIdx.x;
    int b0 = tid * 4;
    float4 Lv4 = *(const float4*)(L + (size_t)v * BP + b0);
    float xt[4] = {Lv4.x, Lv4.y, Lv4.z, Lv4.w};
    float mc[DV][4];
    #pragma unroll
    for (int l = 0; l < DV; ++l) {
        int e = v + l * N_VN;                // vn_idx[e] == e % N_VN
        int c = cn_idx[e];                   // uniform -> scalar load
        float4 s4 = *(const float4*)(ltn + (size_t)e * BP + b0);
        float4 S4 = *(const float4*)(slog + (size_t)c * BP + b0);
        float sa[4] = {s4.x, s4.y, s4.z, s4.w};
        float Sa[4] = {S4.x, S4.y, S4.z, S4.w};
        #pragma unroll
        for (int k = 0; k < 4; ++k) {
            float q = fabsf(sa[k]) - fabsf(Sa[k]);         // sum_others (<= 0)
            float mag = __expf(q);
            float omm = fmaxf(1.0f - mag, 1e-7f);          // 1-mag, clip at 1e-7
            float m = __logf(__fdividef(2.0f - omm, omm)); // 2*atanh(1-omm), >= 0
            // sign: parity_others = parity(slog sign) ^ neg(edge sign)
            unsigned sgn = (__float_as_uint(Sa[k]) ^ __float_as_uint(sa[k])
                            ^ 0x80000000u) & 0x80000000u;
            float msg = __uint_as_float(__float_as_uint(m) ^ sgn);
            mc[l][k] = msg;
            xt[k] += msg;
        }
    }
    if (!LAST) {
        // stats of next-iteration messages: msg_vn' = xt - mc
        #pragma unroll
        for (int l = 0; l < DV; ++l) {
            int e = v + l * N_VN;
            float w = weights[e];
            float o[4];
            #pragma unroll
            for (int k = 0; k < 4; ++k) o[k] = pack_stats(xt[k] - mc[l][k], w);
            *(float4*)(ltn + (size_t)e * BP + b0) = make_float4(o[0], o[1], o[2], o[3]);
        }
    } else {
        if (b0 + 3 < BATCH) {                // xtot stride 1250 (8B aligned only)
            *(float2*)(xtot + (size_t)v * BATCH + b0)     = make_float2(xt[0], xt[1]);
            *(float2*)(xtot + (size_t)v * BATCH + b0 + 2) = make_float2(xt[2], xt[3]);
        } else {
            #pragma unroll
            for (int k = 0; k < 4; ++k)
                if (b0 + k < BATCH) xtot[(size_t)v * BATCH + b0 + k] = xt[k];
        }
    }
    // loss partial (masked to valid batch), softplus(-xt) stable, hw-trans only
    float sp = 0.0f;
    #pragma unroll
    for (int k = 0; k < 4; ++k)
        if (b0 + k < BATCH) {
            float x = xt[k];
            sp += fmaxf(-x, 0.0f) + __logf(1.0f + __expf(-fabsf(x)));
        }
    #pragma unroll
    for (int off = 32; off > 0; off >>= 1)
        sp += __shfl_down(sp, off, 64);
    __shared__ float red[5];
    int lane = tid & 63, wid = tid >> 6;
    if (lane == 0) red[wid] = sp;
    __syncthreads();
    if (tid == 0)
        loss_part[blockIdx.x] = red[0] + red[1] + red[2] + red[3] + red[4];
}

// -------------------------------------------------- c_hat = -x_tot^T (tiled)
__global__ __launch_bounds__(256) void transpose_chat_k(const float* __restrict__ xtot,
                                                        float* __restrict__ chat) {
    __shared__ float tile[32][33];
    int bbase = blockIdx.x * 32;
    int vbase = blockIdx.y * 32;
    int tx = threadIdx.x, ty = threadIdx.y;
    #pragma unroll
    for (int j = 0; j < 4; ++j) {
        int v = vbase + ty + j * 8;
        int b = bbase + tx;
        if (b < BATCH) tile[ty + j * 8][tx] = xtot[(size_t)v * BATCH + b];
    }
    __syncthreads();
    #pragma unroll
    for (int j = 0; j < 4; ++j) {
        int b = bbase + ty + j * 8;
        int v = vbase + tx;
        if (b < BATCH) chat[(size_t)b * N_VN + v] = -tile[tx][ty + j * 8];
    }
}

// ------------------------------------------------- loss: two-stage reduction
__global__ __launch_bounds__(256) void loss_stage1_k(const float* __restrict__ lp,
                                                     double* __restrict__ part) {
    double s = 0.0;
    for (int i = blockIdx.x * 256 + threadIdx.x; i < NPART; i += 64 * 256)
        s += (double)lp[i];
    #pragma unroll
    for (int off = 32; off > 0; off >>= 1)
        s += __shfl_down(s, off, 64);
    __shared__ double red[4];
    int lane = threadIdx.x & 63, wid = threadIdx.x >> 6;
    if (lane == 0) red[wid] = s;
    __syncthreads();
    if (threadIdx.x == 0) part[blockIdx.x] = red[0] + red[1] + red[2] + red[3];
}

__global__ __launch_bounds__(64) void loss_stage2_k(const double* __restrict__ part,
                                                    float* __restrict__ out_loss) {
    double s = part[threadIdx.x];
    #pragma unroll
    for (int off = 32; off > 0; off >>= 1)
        s += __shfl_down(s, off, 64);
    if (threadIdx.x == 0)
        out_loss[0] = (float)(s / ((double)NUM_ITER * (double)BATCH * (double)N_VN));
}

// ---------------------------------------------------------------------- launch
extern "C" void kernel_launch(void* const* d_in, const int* in_sizes, int n_in,
                              void* d_out, int out_size, void* d_ws, size_t ws_size,
                              hipStream_t stream) {
    const float* noise   = (const float*)d_in[0];   // (1250, 8000)
    const float* weights = (const float*)d_in[1];   // (24000,)
    // d_in[2] = vn_idx (unused: vn_idx[e] == e % 8000 by construction)
    const int* cn_idx    = (const int*)d_in[3];     // (24000,)
    const int* ebno      = (const int*)d_in[4];     // scalar int

    float* out      = (float*)d_out;
    float* out_c    = out;                 // (1250,8000) zeros
    float* out_chat = out + 10000000;      // (1250,8000)
    float* out_llr  = out + 20000000;      // (1250,8000)
    float* out_loss = out + 30000000;      // scalar

    // workspace layout (~184.6 MB)
    char* ws = (char*)d_ws;
    float*  ltn       = (float*)(ws);                    // 24000*1280*4 = 122,880,000
    float*  L         = (float*)(ws + 122880000);        //  8000*1280*4 =  40,960,000
    float*  slog      = (float*)(ws + 163840000);        //  4000*1280*4 =  20,480,000
    int*    cn_edges  = (int*)(ws + 184320000);          //  4000*6*4    =      96,000
    int*    cn_cnt    = (int*)(ws + 184416000);          //  4000*4      =      16,000
    float*  loss_part = (float*)(ws + 184432000);        //  5*8000*4    =     160,000
    double* loss_p2   = (double*)(ws + 184592000);       //  64*8        =         512
    float*  xtot      = out_c;  // stride 1250 = exactly 10M floats, no chat overlap

    hipMemsetAsync(cn_cnt, 0, N_CN * sizeof(int), stream);

    build_graph_k<<<dim3((EDGES + 255) / 256), dim3(256), 0, stream>>>(cn_idx, cn_cnt, cn_edges);
    init_llr_k<<<dim3(N_VN / 32, (BATCH + 31) / 32), dim3(32, 8), 0, stream>>>(noise, ebno, out_llr, L);

    for (int it = 0; it < NUM_ITER; ++it) {
        float* lp = loss_part + it * N_VN;   // write-only private slots
        if (it == 0)
            cn_first_k<<<dim3(N_CN), dim3(TPB), 0, stream>>>(L, weights, cn_edges, ltn, slog);
        else
            cn_k<<<dim3(N_CN), dim3(TPB), 0, stream>>>(ltn, cn_edges, slog);
        if (it == NUM_ITER - 1)
            vn_k<true ><<<dim3(N_VN), dim3(TPB), 0, stream>>>(ltn, L, weights, cn_idx, slog, xtot, lp);
        else
            vn_k<false><<<dim3(N_VN), dim3(TPB), 0, stream>>>(ltn, L, weights, cn_idx, slog, xtot, lp);
    }

    transpose_chat_k<<<dim3((BATCH + 31) / 32, N_VN / 32), dim3(32, 8), 0, stream>>>(xtot, out_chat);
    hipMemsetAsync(out_c, 0, 10000000 * sizeof(float), stream);  // c = zeros (after xtot read)
    loss_stage1_k<<<dim3(64), dim3(256), 0, stream>>>(loss_part, loss_p2);
    loss_stage2_k<<<dim3(1), dim3(64), 0, stream>>>(loss_p2, out_loss);
}

// Round 5
// 623.821 us; speedup vs baseline: 2.7350x; 1.0374x over previous
//
#include <hip/hip_runtime.h>
#include <math.h>

constexpr int N_VN   = 8000;
constexpr int N_CN   = 4000;
constexpr int DV     = 3;
constexpr int DC     = 6;
constexpr int EDGES  = N_VN * DV;   // 24000
constexpr int BATCH  = 1250;
constexpr int BP     = 1280;        // padded batch stride (=320 float4)
constexpr int NUM_ITER = 5;
constexpr float LLR_MAX = 20.0f;
constexpr int TPB    = 320;         // 320 thr x 4 floats = 1280 = BP (5 waves)
constexpr int NPART  = NUM_ITER * N_VN;      // 40000 loss partials
constexpr float PCLIP = 1.0f - 1e-7f;        // 0.99999988f, matches ref's f32 clip

// Signed t = tanh(clip(mv*w, +-20)/2), |t| floored at EPS=1e-12 (ref semantics:
// mag uses max(|t|,EPS), sign uses (mw<0); -0 maps to +, matching t<0 test).
// t never +-0 after floor -> product sign == parity of negative signs.
__device__ __forceinline__ float signed_t(float mv, float w) {
    float mw = fminf(fmaxf(mv * w, -LLR_MAX), LLR_MAX);
    float ex = __expf(-fabsf(mw));
    float t  = fmaxf(__fdividef(1.0f - ex, 1.0f + ex), 1e-12f);
    return (mw < 0.0f) ? -t : t;
}

// ---------------------------------------------------------------- graph build
__global__ __launch_bounds__(256) void build_graph_k(const int* __restrict__ cn_idx,
                                                     int* __restrict__ cnt,
                                                     int* __restrict__ cn_edges) {
    int e = blockIdx.x * 256 + threadIdx.x;
    if (e >= EDGES) return;
    int c = cn_idx[e];
    int slot = atomicAdd(&cnt[c], 1);   // order irrelevant (product commutes)
    cn_edges[c * DC + slot] = e;
}

// --------------------------------------------------- init: llr out + L = -llr^T
__global__ __launch_bounds__(256) void init_llr_k(const float* __restrict__ noise,
                                                  const int* __restrict__ ebno,
                                                  float* __restrict__ llr_out,
                                                  float* __restrict__ L) {
    __shared__ float tile[32][33];
    __shared__ float hs[2];
    int tx = threadIdx.x, ty = threadIdx.y;
    if (tx == 0 && ty == 0) {
        double sig2 = 2.0 * pow(10.0, (double)ebno[0] * 0.1);  // 4/no
        hs[0] = (float)(sig2 * 0.5);
        hs[1] = (float)sqrt(sig2);
    }
    __syncthreads();
    float h = hs[0], s = hs[1];
    int vbase = blockIdx.x * 32;
    int bbase = blockIdx.y * 32;
    #pragma unroll
    for (int j = 0; j < 4; ++j) {
        int v = vbase + tx;
        int b = bbase + ty + j * 8;
        if (b < BATCH) {
            float val = noise[b * N_VN + v];
            tile[ty + j * 8][tx] = val;
            llr_out[b * N_VN + v] = -h + s * val;
        }
    }
    __syncthreads();
    #pragma unroll
    for (int j = 0; j < 4; ++j) {
        int b = bbase + tx;
        int v = vbase + ty + j * 8;
        if (b < BATCH) L[v * BP + b] = h - s * tile[tx][ty + j * 8];  // L=-llr^T
    }
}

// --------------------------------- iter 0 CN: t from L, write tn + tprod
__global__ __launch_bounds__(TPB) void cn_first_k(const float* __restrict__ L,
                                                  const float* __restrict__ weights,
                                                  const int* __restrict__ cn_edges,
                                                  float* __restrict__ tn,
                                                  float* __restrict__ tprod) {
    int c = blockIdx.x;
    int b0 = threadIdx.x * 4;
    float prod[4] = {1.f, 1.f, 1.f, 1.f};
    #pragma unroll
    for (int j = 0; j < DC; ++j) {
        int e = cn_edges[c * DC + j];            // uniform -> scalar load
        int v = e; if (v >= 2 * N_VN) v -= 2 * N_VN; else if (v >= N_VN) v -= N_VN;
        float w = weights[e];
        float4 Lv = *(const float4*)(L + (size_t)v * BP + b0);
        float a[4] = {Lv.x, Lv.y, Lv.z, Lv.w};
        float o[4];
        #pragma unroll
        for (int k = 0; k < 4; ++k) {
            float t = signed_t(a[k], w);
            o[k] = t;
            prod[k] *= t;
        }
        *(float4*)(tn + (size_t)e * BP + b0) = make_float4(o[0], o[1], o[2], o[3]);
    }
    *(float4*)(tprod + (size_t)c * BP + b0) = make_float4(prod[0], prod[1], prod[2], prod[3]);
}

// --------------------------------------- CN: pure 6-term product of signed t
__global__ __launch_bounds__(TPB) void cn_k(const float* __restrict__ tn,
                                            const int* __restrict__ cn_edges,
                                            float* __restrict__ tprod) {
    int c = blockIdx.x;
    int b0 = threadIdx.x * 4;
    float prod[4] = {1.f, 1.f, 1.f, 1.f};
    #pragma unroll
    for (int j = 0; j < DC; ++j) {
        int e = cn_edges[c * DC + j];
        float4 s4 = *(const float4*)(tn + (size_t)e * BP + b0);
        prod[0] *= s4.x; prod[1] *= s4.y; prod[2] *= s4.z; prod[3] *= s4.w;
    }
    *(float4*)(tprod + (size_t)c * BP + b0) = make_float4(prod[0], prod[1], prod[2], prod[3]);
}

// ------------------------------------------------------------------ VN update
template <bool LAST>
__global__ __launch_bounds__(TPB) void vn_k(float* __restrict__ tn,
                                            const float* __restrict__ L,
                                            const float* __restrict__ weights,
                                            const int* __restrict__ cn_idx,
                                            const float* __restrict__ tprod,
                                            float* __restrict__ xtot,
                                            float* __restrict__ loss_part) {
    int v = blockIdx.x;
    int tid = threadIdx.x;
    int b0 = tid * 4;
    float4 Lv4 = *(const float4*)(L + (size_t)v * BP + b0);
    float xt[4] = {Lv4.x, Lv4.y, Lv4.z, Lv4.w};
    float mc[DV][4];
    #pragma unroll
    for (int l = 0; l < DV; ++l) {
        int e = v + l * N_VN;                // vn_idx[e] == e % N_VN
        int c = cn_idx[e];                   // uniform -> scalar load
        float4 t4 = *(const float4*)(tn + (size_t)e * BP + b0);
        float4 T4 = *(const float4*)(tprod + (size_t)c * BP + b0);
        float ta[4] = {t4.x, t4.y, t4.z, t4.w};
        float Ta[4] = {T4.x, T4.y, T4.z, T4.w};
        #pragma unroll
        for (int k = 0; k < 4; ++k) {
            float mag = __fdividef(Ta[k], ta[k]);       // signed prod of others
            float p = fminf(fmaxf(mag, -PCLIP), PCLIP); // ref's clip
            float msg = __logf(__fdividef(1.0f + p, 1.0f - p)); // 2*atanh(p)
            mc[l][k] = msg;
            xt[k] += msg;
        }
    }
    if (!LAST) {
        // next-iteration t: msg_vn' = xt - mc
        #pragma unroll
        for (int l = 0; l < DV; ++l) {
            int e = v + l * N_VN;
            float w = weights[e];
            float o[4];
            #pragma unroll
            for (int k = 0; k < 4; ++k) o[k] = signed_t(xt[k] - mc[l][k], w);
            *(float4*)(tn + (size_t)e * BP + b0) = make_float4(o[0], o[1], o[2], o[3]);
        }
    } else {
        if (b0 + 3 < BATCH) {                // xtot stride 1250 (8B aligned only)
            *(float2*)(xtot + (size_t)v * BATCH + b0)     = make_float2(xt[0], xt[1]);
            *(float2*)(xtot + (size_t)v * BATCH + b0 + 2) = make_float2(xt[2], xt[3]);
        } else {
            #pragma unroll
            for (int k = 0; k < 4; ++k)
                if (b0 + k < BATCH) xtot[(size_t)v * BATCH + b0 + k] = xt[k];
        }
    }
    // loss partial (masked to valid batch), softplus(-xt) stable, hw-trans only
    float sp = 0.0f;
    #pragma unroll
    for (int k = 0; k < 4; ++k)
        if (b0 + k < BATCH) {
            float x = xt[k];
            sp += fmaxf(-x, 0.0f) + __logf(1.0f + __expf(-fabsf(x)));
        }
    #pragma unroll
    for (int off = 32; off > 0; off >>= 1)
        sp += __shfl_down(sp, off, 64);
    __shared__ float red[5];
    int lane = tid & 63, wid = tid >> 6;
    if (lane == 0) red[wid] = sp;
    __syncthreads();
    if (tid == 0)
        loss_part[blockIdx.x] = red[0] + red[1] + red[2] + red[3] + red[4];
}

// -------------------------------------------------- c_hat = -x_tot^T (tiled)
__global__ __launch_bounds__(256) void transpose_chat_k(const float* __restrict__ xtot,
                                                        float* __restrict__ chat) {
    __shared__ float tile[32][33];
    int bbase = blockIdx.x * 32;
    int vbase = blockIdx.y * 32;
    int tx = threadIdx.x, ty = threadIdx.y;
    #pragma unroll
    for (int j = 0; j < 4; ++j) {
        int v = vbase + ty + j * 8;
        int b = bbase + tx;
        if (b < BATCH) tile[ty + j * 8][tx] = xtot[(size_t)v * BATCH + b];
    }
    __syncthreads();
    #pragma unroll
    for (int j = 0; j < 4; ++j) {
        int b = bbase + ty + j * 8;
        int v = vbase + tx;
        if (b < BATCH) chat[(size_t)b * N_VN + v] = -tile[tx][ty + j * 8];
    }
}

// ------------------------------------------------- loss: two-stage reduction
__global__ __launch_bounds__(256) void loss_stage1_k(const float* __restrict__ lp,
                                                     double* __restrict__ part) {
    double s = 0.0;
    for (int i = blockIdx.x * 256 + threadIdx.x; i < NPART; i += 64 * 256)
        s += (double)lp[i];
    #pragma unroll
    for (int off = 32; off > 0; off >>= 1)
        s += __shfl_down(s, off, 64);
    __shared__ double red[4];
    int lane = threadIdx.x & 63, wid = threadIdx.x >> 6;
    if (lane == 0) red[wid] = s;
    __syncthreads();
    if (threadIdx.x == 0) part[blockIdx.x] = red[0] + red[1] + red[2] + red[3];
}

__global__ __launch_bounds__(64) void loss_stage2_k(const double* __restrict__ part,
                                                    float* __restrict__ out_loss) {
    double s = part[threadIdx.x];
    #pragma unroll
    for (int off = 32; off > 0; off >>= 1)
        s += __shfl_down(s, off, 64);
    if (threadIdx.x == 0)
        out_loss[0] = (float)(s / ((double)NUM_ITER * (double)BATCH * (double)N_VN));
}

// ---------------------------------------------------------------------- launch
extern "C" void kernel_launch(void* const* d_in, const int* in_sizes, int n_in,
                              void* d_out, int out_size, void* d_ws, size_t ws_size,
                              hipStream_t stream) {
    const float* noise   = (const float*)d_in[0];   // (1250, 8000)
    const float* weights = (const float*)d_in[1];   // (24000,)
    // d_in[2] = vn_idx (unused: vn_idx[e] == e % 8000 by construction)
    const int* cn_idx    = (const int*)d_in[3];     // (24000,)
    const int* ebno      = (const int*)d_in[4];     // scalar int

    float* out      = (float*)d_out;
    float* out_c    = out;                 // (1250,8000) zeros
    float* out_chat = out + 10000000;      // (1250,8000)
    float* out_llr  = out + 20000000;      // (1250,8000)
    float* out_loss = out + 30000000;      // scalar

    // workspace layout (~184.6 MB)
    char* ws = (char*)d_ws;
    float*  tn        = (float*)(ws);                    // 24000*1280*4 = 122,880,000
    float*  L         = (float*)(ws + 122880000);        //  8000*1280*4 =  40,960,000
    float*  tprod     = (float*)(ws + 163840000);        //  4000*1280*4 =  20,480,000
    int*    cn_edges  = (int*)(ws + 184320000);          //  4000*6*4    =      96,000
    int*    cn_cnt    = (int*)(ws + 184416000);          //  4000*4      =      16,000
    float*  loss_part = (float*)(ws + 184432000);        //  5*8000*4    =     160,000
    double* loss_p2   = (double*)(ws + 184592000);       //  64*8        =         512
    float*  xtot      = out_c;  // stride 1250 = exactly 10M floats, no chat overlap

    hipMemsetAsync(cn_cnt, 0, N_CN * sizeof(int), stream);

    build_graph_k<<<dim3((EDGES + 255) / 256), dim3(256), 0, stream>>>(cn_idx, cn_cnt, cn_edges);
    init_llr_k<<<dim3(N_VN / 32, (BATCH + 31) / 32), dim3(32, 8), 0, stream>>>(noise, ebno, out_llr, L);

    for (int it = 0; it < NUM_ITER; ++it) {
        float* lp = loss_part + it * N_VN;   // write-only private slots
        if (it == 0)
            cn_first_k<<<dim3(N_CN), dim3(TPB), 0, stream>>>(L, weights, cn_edges, tn, tprod);
        else
            cn_k<<<dim3(N_CN), dim3(TPB), 0, stream>>>(tn, cn_edges, tprod);
        if (it == NUM_ITER - 1)
            vn_k<true ><<<dim3(N_VN), dim3(TPB), 0, stream>>>(tn, L, weights, cn_idx, tprod, xtot, lp);
        else
            vn_k<false><<<dim3(N_VN), dim3(TPB), 0, stream>>>(tn, L, weights, cn_idx, tprod, xtot, lp);
    }

    transpose_chat_k<<<dim3((BATCH + 31) / 32, N_VN / 32), dim3(32, 8), 0, stream>>>(xtot, out_chat);
    hipMemsetAsync(out_c, 0, 10000000 * sizeof(float), stream);  // c = zeros (after xtot read)
    loss_stage1_k<<<dim3(64), dim3(256), 0, stream>>>(loss_part, loss_p2);
    loss_stage2_k<<<dim3(1), dim3(64), 0, stream>>>(loss_p2, out_loss);
}

// Round 6
// 586.187 us; speedup vs baseline: 2.9105x; 1.0642x over previous
//
#include <hip/hip_runtime.h>
#include <math.h>

constexpr int N_VN   = 8000;
constexpr int N_CN   = 4000;
constexpr int DV     = 3;
constexpr int DC     = 6;
constexpr int EDGES  = N_VN * DV;   // 24000
constexpr int BATCH  = 1250;
constexpr int BP     = 1280;        // padded batch stride (=320 float4)
constexpr int NUM_ITER = 5;
constexpr float LLR_MAX = 20.0f;
constexpr int TPB    = 320;         // 320 thr x 4 floats = 1280 = BP (5 waves)
constexpr int NPART  = NUM_ITER * N_VN;      // 40000 loss partials
// 2*atanh(clip) with clip = f32(1-1e-7) = 1 - 2^-23: log((2-2^-23)/2^-23)
constexpr float MSGMAX = 16.635532f;
constexpr float FFLOOR = 2e-12f;    // floor on (1-ex): reproduces ref's |t|>=1e-12

// Packed edge stat: ex = exp(-|mw|) in (0,1], sign bit = sign(mw).
// t = tanh(mw/2) = (1-ex)/(1+ex) is recovered as floored factors f/d.
__device__ __forceinline__ float pack_ex(float mv, float w) {
    float mw = fminf(fmaxf(mv * w, -LLR_MAX), LLR_MAX);
    float ex = __expf(-fabsf(mw));
    unsigned sgn = __float_as_uint(mw) & 0x80000000u;
    return __uint_as_float(__float_as_uint(ex) | sgn);
}

// ---------------------------------------------------------------- graph build
__global__ __launch_bounds__(256) void build_graph_k(const int* __restrict__ cn_idx,
                                                     int* __restrict__ cnt,
                                                     int* __restrict__ cn_edges) {
    int e = blockIdx.x * 256 + threadIdx.x;
    if (e >= EDGES) return;
    int c = cn_idx[e];
    int slot = atomicAdd(&cnt[c], 1);   // order irrelevant (product commutes)
    cn_edges[c * DC + slot] = e;
}

// --------------------------------------------------- init: llr out + L = -llr^T
__global__ __launch_bounds__(256) void init_llr_k(const float* __restrict__ noise,
                                                  const int* __restrict__ ebno,
                                                  float* __restrict__ llr_out,
                                                  float* __restrict__ L) {
    __shared__ float tile[32][33];
    __shared__ float hs[2];
    int tx = threadIdx.x, ty = threadIdx.y;
    if (tx == 0 && ty == 0) {
        double sig2 = 2.0 * pow(10.0, (double)ebno[0] * 0.1);  // 4/no
        hs[0] = (float)(sig2 * 0.5);
        hs[1] = (float)sqrt(sig2);
    }
    __syncthreads();
    float h = hs[0], s = hs[1];
    int vbase = blockIdx.x * 32;
    int bbase = blockIdx.y * 32;
    #pragma unroll
    for (int j = 0; j < 4; ++j) {
        int v = vbase + tx;
        int b = bbase + ty + j * 8;
        if (b < BATCH) {
            float val = noise[b * N_VN + v];
            tile[ty + j * 8][tx] = val;
            llr_out[b * N_VN + v] = -h + s * val;
        }
    }
    __syncthreads();
    #pragma unroll
    for (int j = 0; j < 4; ++j) {
        int b = bbase + tx;
        int v = vbase + ty + j * 8;
        if (b < BATCH) L[v * BP + b] = h - s * tile[tx][ty + j * 8];  // L=-llr^T
    }
}

// ------------------ iter 0 CN: products straight from L, write tprod ONLY
__global__ __launch_bounds__(TPB) void cn_first_k(const float* __restrict__ L,
                                                  const float* __restrict__ weights,
                                                  const int* __restrict__ cn_edges,
                                                  float* __restrict__ tprod) {
    int c = blockIdx.x;
    int b0 = threadIdx.x * 4;
    float num[4] = {1.f, 1.f, 1.f, 1.f}, den[4] = {1.f, 1.f, 1.f, 1.f};
    unsigned sx[4] = {0u, 0u, 0u, 0u};
    #pragma unroll
    for (int j = 0; j < DC; ++j) {
        int e = cn_edges[c * DC + j];            // uniform -> scalar load
        int v = e; if (v >= 2 * N_VN) v -= 2 * N_VN; else if (v >= N_VN) v -= N_VN;
        float w = weights[e];
        float4 Lv = *(const float4*)(L + (size_t)v * BP + b0);
        float a[4] = {Lv.x, Lv.y, Lv.z, Lv.w};
        #pragma unroll
        for (int k = 0; k < 4; ++k) {
            float se = pack_ex(a[k], w);
            float ex = fabsf(se);
            num[k] *= fmaxf(1.0f - ex, FFLOOR);
            den[k] *= 1.0f + ex;
            sx[k] ^= __float_as_uint(se);
        }
    }
    float o[4];
    #pragma unroll
    for (int k = 0; k < 4; ++k) {
        float T = __fdividef(num[k], den[k]);    // >= 0 (may underflow to +0)
        o[k] = __uint_as_float(__float_as_uint(T) | (sx[k] & 0x80000000u));
    }
    *(float4*)(tprod + (size_t)c * BP + b0) = make_float4(o[0], o[1], o[2], o[3]);
}

// ----------------- CN: product of floored (1-ex)/(1+ex), one divide per elem
__global__ __launch_bounds__(TPB) void cn_k(const float* __restrict__ exn,
                                            const int* __restrict__ cn_edges,
                                            float* __restrict__ tprod) {
    int c = blockIdx.x;
    int b0 = threadIdx.x * 4;
    float num[4] = {1.f, 1.f, 1.f, 1.f}, den[4] = {1.f, 1.f, 1.f, 1.f};
    unsigned sx[4] = {0u, 0u, 0u, 0u};
    #pragma unroll
    for (int j = 0; j < DC; ++j) {
        int e = cn_edges[c * DC + j];
        float4 s4 = *(const float4*)(exn + (size_t)e * BP + b0);
        float a[4] = {s4.x, s4.y, s4.z, s4.w};
        #pragma unroll
        for (int k = 0; k < 4; ++k) {
            float ex = fabsf(a[k]);
            num[k] *= fmaxf(1.0f - ex, FFLOOR);
            den[k] *= 1.0f + ex;
            sx[k] ^= __float_as_uint(a[k]);
        }
    }
    float o[4];
    #pragma unroll
    for (int k = 0; k < 4; ++k) {
        float T = __fdividef(num[k], den[k]);
        o[k] = __uint_as_float(__float_as_uint(T) | (sx[k] & 0x80000000u));
    }
    *(float4*)(tprod + (size_t)c * BP + b0) = make_float4(o[0], o[1], o[2], o[3]);
}

// ------------------------------------------------------------------ VN update
template <bool FIRST, bool LAST>
__global__ __launch_bounds__(TPB) void vn_k(float* __restrict__ exn,
                                            const float* __restrict__ L,
                                            const float* __restrict__ weights,
                                            const int* __restrict__ cn_idx,
                                            const float* __restrict__ tprod,
                                            float* __restrict__ xtot,
                                            float* __restrict__ loss_part) {
    int v = blockIdx.x;
    int tid = threadIdx.x;
    int b0 = tid * 4;
    float4 Lv4 = *(const float4*)(L + (size_t)v * BP + b0);
    float Lv[4] = {Lv4.x, Lv4.y, Lv4.z, Lv4.w};
    float xt[4] = {Lv[0], Lv[1], Lv[2], Lv[3]};
    float mc[DV][4];
    float wl[DV];
    #pragma unroll
    for (int l = 0; l < DV; ++l) {
        int e = v + l * N_VN;                // vn_idx[e] == e % N_VN
        int c = cn_idx[e];                   // uniform -> scalar load
        wl[l] = weights[e];
        float se[4];
        if (FIRST) {
            #pragma unroll
            for (int k = 0; k < 4; ++k) se[k] = pack_ex(Lv[k], wl[l]);
        } else {
            float4 s4 = *(const float4*)(exn + (size_t)e * BP + b0);
            se[0] = s4.x; se[1] = s4.y; se[2] = s4.z; se[3] = s4.w;
        }
        float4 T4 = *(const float4*)(tprod + (size_t)c * BP + b0);
        float Ta[4] = {T4.x, T4.y, T4.z, T4.w};
        #pragma unroll
        for (int k = 0; k < 4; ++k) {
            float ex = fabsf(se[k]);
            float A  = fabsf(Ta[k]);
            float f  = fmaxf(1.0f - ex, FFLOOR);
            float g  = fmaf(A, ex, A);               // A*(1+ex)
            // 2*atanh(p), p = prod_others: (1+p)/(1-p) == (f+g)/(f-g)
            float r  = __fdividef(f + g, f - g);
            float ma = fminf(__logf(r), MSGMAX);     // inf/NaN corner -> clamp
            unsigned sg = (__float_as_uint(se[k]) ^ __float_as_uint(Ta[k]))
                          & 0x80000000u;
            float msg = __uint_as_float(__float_as_uint(ma) ^ sg);
            mc[l][k] = msg;
            xt[k] += msg;
        }
    }
    if (!LAST) {
        // next-iteration packed ex: msg_vn' = xt - mc
        #pragma unroll
        for (int l = 0; l < DV; ++l) {
            int e = v + l * N_VN;
            float o[4];
            #pragma unroll
            for (int k = 0; k < 4; ++k) o[k] = pack_ex(xt[k] - mc[l][k], wl[l]);
            *(float4*)(exn + (size_t)e * BP + b0) = make_float4(o[0], o[1], o[2], o[3]);
        }
    } else {
        if (b0 + 3 < BATCH) {                // xtot stride 1250 (8B aligned only)
            *(float2*)(xtot + (size_t)v * BATCH + b0)     = make_float2(xt[0], xt[1]);
            *(float2*)(xtot + (size_t)v * BATCH + b0 + 2) = make_float2(xt[2], xt[3]);
        } else {
            #pragma unroll
            for (int k = 0; k < 4; ++k)
                if (b0 + k < BATCH) xtot[(size_t)v * BATCH + b0 + k] = xt[k];
        }
    }
    // loss partial (masked to valid batch), softplus(-xt) stable, hw-trans only
    float sp = 0.0f;
    #pragma unroll
    for (int k = 0; k < 4; ++k)
        if (b0 + k < BATCH) {
            float x = xt[k];
            sp += fmaxf(-x, 0.0f) + __logf(1.0f + __expf(-fabsf(x)));
        }
    #pragma unroll
    for (int off = 32; off > 0; off >>= 1)
        sp += __shfl_down(sp, off, 64);
    __shared__ float red[5];
    int lane = tid & 63, wid = tid >> 6;
    if (lane == 0) red[wid] = sp;
    __syncthreads();
    if (tid == 0)
        loss_part[blockIdx.x] = red[0] + red[1] + red[2] + red[3] + red[4];
}

// -------------------------------------------------- c_hat = -x_tot^T (tiled)
__global__ __launch_bounds__(256) void transpose_chat_k(const float* __restrict__ xtot,
                                                        float* __restrict__ chat) {
    __shared__ float tile[32][33];
    int bbase = blockIdx.x * 32;
    int vbase = blockIdx.y * 32;
    int tx = threadIdx.x, ty = threadIdx.y;
    #pragma unroll
    for (int j = 0; j < 4; ++j) {
        int v = vbase + ty + j * 8;
        int b = bbase + tx;
        if (b < BATCH) tile[ty + j * 8][tx] = xtot[(size_t)v * BATCH + b];
    }
    __syncthreads();
    #pragma unroll
    for (int j = 0; j < 4; ++j) {
        int b = bbase + ty + j * 8;
        int v = vbase + tx;
        if (b < BATCH) chat[(size_t)b * N_VN + v] = -tile[tx][ty + j * 8];
    }
}

// ------------------------------------------------- loss: two-stage reduction
__global__ __launch_bounds__(256) void loss_stage1_k(const float* __restrict__ lp,
                                                     double* __restrict__ part) {
    double s = 0.0;
    for (int i = blockIdx.x * 256 + threadIdx.x; i < NPART; i += 64 * 256)
        s += (double)lp[i];
    #pragma unroll
    for (int off = 32; off > 0; off >>= 1)
        s += __shfl_down(s, off, 64);
    __shared__ double red[4];
    int lane = threadIdx.x & 63, wid = threadIdx.x >> 6;
    if (lane == 0) red[wid] = s;
    __syncthreads();
    if (threadIdx.x == 0) part[blockIdx.x] = red[0] + red[1] + red[2] + red[3];
}

__global__ __launch_bounds__(64) void loss_stage2_k(const double* __restrict__ part,
                                                    float* __restrict__ out_loss) {
    double s = part[threadIdx.x];
    #pragma unroll
    for (int off = 32; off > 0; off >>= 1)
        s += __shfl_down(s, off, 64);
    if (threadIdx.x == 0)
        out_loss[0] = (float)(s / ((double)NUM_ITER * (double)BATCH * (double)N_VN));
}

// ---------------------------------------------------------------------- launch
extern "C" void kernel_launch(void* const* d_in, const int* in_sizes, int n_in,
                              void* d_out, int out_size, void* d_ws, size_t ws_size,
                              hipStream_t stream) {
    const float* noise   = (const float*)d_in[0];   // (1250, 8000)
    const float* weights = (const float*)d_in[1];   // (24000,)
    // d_in[2] = vn_idx (unused: vn_idx[e] == e % 8000 by construction)
    const int* cn_idx    = (const int*)d_in[3];     // (24000,)
    const int* ebno      = (const int*)d_in[4];     // scalar int

    float* out      = (float*)d_out;
    float* out_c    = out;                 // (1250,8000) zeros
    float* out_chat = out + 10000000;      // (1250,8000)
    float* out_llr  = out + 20000000;      // (1250,8000)
    float* out_loss = out + 30000000;      // scalar

    // workspace layout (~184.6 MB)
    char* ws = (char*)d_ws;
    float*  exn       = (float*)(ws);                    // 24000*1280*4 = 122,880,000
    float*  L         = (float*)(ws + 122880000);        //  8000*1280*4 =  40,960,000
    float*  tprod     = (float*)(ws + 163840000);        //  4000*1280*4 =  20,480,000
    int*    cn_edges  = (int*)(ws + 184320000);          //  4000*6*4    =      96,000
    int*    cn_cnt    = (int*)(ws + 184416000);          //  4000*4      =      16,000
    float*  loss_part = (float*)(ws + 184432000);        //  5*8000*4    =     160,000
    double* loss_p2   = (double*)(ws + 184592000);       //  64*8        =         512
    float*  xtot      = out_c;  // stride 1250 = exactly 10M floats, no chat overlap

    hipMemsetAsync(cn_cnt, 0, N_CN * sizeof(int), stream);

    build_graph_k<<<dim3((EDGES + 255) / 256), dim3(256), 0, stream>>>(cn_idx, cn_cnt, cn_edges);
    init_llr_k<<<dim3(N_VN / 32, (BATCH + 31) / 32), dim3(32, 8), 0, stream>>>(noise, ebno, out_llr, L);

    for (int it = 0; it < NUM_ITER; ++it) {
        float* lp = loss_part + it * N_VN;   // write-only private slots
        if (it == 0)
            cn_first_k<<<dim3(N_CN), dim3(TPB), 0, stream>>>(L, weights, cn_edges, tprod);
        else
            cn_k<<<dim3(N_CN), dim3(TPB), 0, stream>>>(exn, cn_edges, tprod);
        if (it == 0)
            vn_k<true , false><<<dim3(N_VN), dim3(TPB), 0, stream>>>(exn, L, weights, cn_idx, tprod, xtot, lp);
        else if (it == NUM_ITER - 1)
            vn_k<false, true ><<<dim3(N_VN), dim3(TPB), 0, stream>>>(exn, L, weights, cn_idx, tprod, xtot, lp);
        else
            vn_k<false, false><<<dim3(N_VN), dim3(TPB), 0, stream>>>(exn, L, weights, cn_idx, tprod, xtot, lp);
    }

    transpose_chat_k<<<dim3((BATCH + 31) / 32, N_VN / 32), dim3(32, 8), 0, stream>>>(xtot, out_chat);
    hipMemsetAsync(out_c, 0, 10000000 * sizeof(float), stream);  // c = zeros (after xtot read)
    loss_stage1_k<<<dim3(64), dim3(256), 0, stream>>>(loss_part, loss_p2);
    loss_stage2_k<<<dim3(1), dim3(64), 0, stream>>>(loss_p2, out_loss);
}